// Round 1
// baseline (916.029 us; speedup 1.0000x reference)
//
#include <hip/hip_runtime.h>

// patches_generator: bilinear grid_sample (border, align_corners=False)
// fm:   [N=16, C=128, H=112, W=112] f32
// grid: [N, P=98, 16, 16, 2] f32  (x,y) in [-1,1]
// out:  [N, P, C, 16, 16] f32

#define NN 16
#define CC 128
#define HH 112
#define WW 112
#define PP 98
#define HWs (HH * WW)
#define PTS 256   // 16x16 sample points per patch

__global__ __launch_bounds__(256) void patches_kernel(
    const float* __restrict__ fm,
    const float* __restrict__ grid,
    float* __restrict__ out) {
  const int p = blockIdx.x;   // patch
  const int n = blockIdx.y;   // batch
  const int t = threadIdx.x;  // sample point within patch (hg*16+wg)
  const int blk = n * PP + p;

  // coalesced float2 load of (gx, gy)
  const float2 g = reinterpret_cast<const float2*>(grid)[(size_t)blk * PTS + t];

  // unnormalize (align_corners=False) then clamp to border
  float x = fminf(fmaxf(fmaf(g.x, (float)WW * 0.5f, (float)WW * 0.5f - 0.5f), 0.0f), (float)(WW - 1));
  float y = fminf(fmaxf(fmaf(g.y, (float)HH * 0.5f, (float)HH * 0.5f - 0.5f), 0.0f), (float)(HH - 1));

  float x0f = floorf(x), y0f = floorf(y);
  float wx = x - x0f, wy = y - y0f;
  int x0 = (int)x0f;
  int y0 = (int)y0f;
  int x1 = min(x0 + 1, WW - 1);
  int y1 = min(y0 + 1, HH - 1);

  // per-lane tap offsets (loop-invariant across channels)
  const int o00 = y0 * WW + x0;
  const int o01 = y0 * WW + x1;
  const int o10 = y1 * WW + x0;
  const int o11 = y1 * WW + x1;

  const float w00 = (1.0f - wy) * (1.0f - wx);
  const float w01 = (1.0f - wy) * wx;
  const float w10 = wy * (1.0f - wx);
  const float w11 = wy * wx;

  const float* __restrict__ fb = fm + (size_t)n * CC * HWs;
  float* __restrict__ ob = out + (size_t)blk * CC * PTS + t;

#pragma unroll 4
  for (int c = 0; c < CC; ++c) {
    const float* __restrict__ pc = fb + c * HWs;  // wave-uniform base per channel
    float v = pc[o00] * w00;
    v = fmaf(pc[o01], w01, v);
    v = fmaf(pc[o10], w10, v);
    v = fmaf(pc[o11], w11, v);
    ob[(size_t)c * PTS] = v;  // coalesced: 256 consecutive floats
  }
}

extern "C" void kernel_launch(void* const* d_in, const int* in_sizes, int n_in,
                              void* d_out, int out_size, void* d_ws, size_t ws_size,
                              hipStream_t stream) {
  const float* fm = (const float*)d_in[0];
  const float* grid = (const float*)d_in[1];
  float* out = (float*)d_out;

  dim3 grd(PP, NN);
  dim3 blk(256);
  patches_kernel<<<grd, blk, 0, stream>>>(fm, grid, out);
}

// Round 2
// 673.110 us; speedup vs baseline: 1.3609x; 1.3609x over previous
//
#include <hip/hip_runtime.h>

// patches_generator: bilinear grid_sample (border, align_corners=False)
// fm:   [N=16, C=128, H=112, W=112] f32
// grid: [N, P=98, 16, 16, 2] f32  (x,y) in [-1,1]
// out:  [N, P, C, 16, 16] f32

#define NN 16
#define CC 128
#define HH 112
#define WW 112
#define PP 98
#define HWs (HH * WW)
#define PTS 256     // 16x16 sample points per patch
#define CSPLIT 4    // channel chunks per patch (blocks in z)
#define CCHUNK (CC / CSPLIT)  // 32 channels per block

__global__ __launch_bounds__(256) void patches_kernel(
    const float* __restrict__ fm,
    const float* __restrict__ grid,
    float* __restrict__ out) {
  const int p = blockIdx.x;   // patch
  const int n = blockIdx.y;   // batch
  const int c0 = blockIdx.z * CCHUNK;
  const int t = threadIdx.x;  // sample point within patch (hg*16+wg)
  const int blk = n * PP + p;

  // coalesced float2 load of (gx, gy)
  const float2 g = reinterpret_cast<const float2*>(grid)[(size_t)blk * PTS + t];

  // unnormalize (align_corners=False) then clamp to border
  float x = fminf(fmaxf(fmaf(g.x, (float)WW * 0.5f, (float)WW * 0.5f - 0.5f), 0.0f), (float)(WW - 1));
  float y = fminf(fmaxf(fmaf(g.y, (float)HH * 0.5f, (float)HH * 0.5f - 0.5f), 0.0f), (float)(HH - 1));

  float x0f = floorf(x), y0f = floorf(y);
  float wx = x - x0f, wy = y - y0f;
  int x0 = (int)x0f;
  int y0 = (int)y0f;
  int x1 = min(x0 + 1, WW - 1);
  int y1 = min(y0 + 1, HH - 1);

  // per-lane tap offsets (loop-invariant across channels)
  const int o00 = y0 * WW + x0;
  const int o01 = y0 * WW + x1;
  const int o10 = y1 * WW + x0;
  const int o11 = y1 * WW + x1;

  const float w00 = (1.0f - wy) * (1.0f - wx);
  const float w01 = (1.0f - wy) * wx;
  const float w10 = wy * (1.0f - wx);
  const float w11 = wy * wx;

  const float* __restrict__ fb = fm + (size_t)n * CC * HWs + (size_t)c0 * HWs;
  float* __restrict__ ob = out + (size_t)blk * CC * PTS + (size_t)c0 * PTS + t;

#pragma unroll 8
  for (int c = 0; c < CCHUNK; ++c) {
    const float* __restrict__ pc = fb + c * HWs;  // wave-uniform base per channel
    float v = pc[o00] * w00;
    v = fmaf(pc[o01], w01, v);
    v = fmaf(pc[o10], w10, v);
    v = fmaf(pc[o11], w11, v);
    // streaming output, never re-read: bypass L2 so fm gathers keep the cache
    __builtin_nontemporal_store(v, &ob[(size_t)c * PTS]);
  }
}

extern "C" void kernel_launch(void* const* d_in, const int* in_sizes, int n_in,
                              void* d_out, int out_size, void* d_ws, size_t ws_size,
                              hipStream_t stream) {
  const float* fm = (const float*)d_in[0];
  const float* grid = (const float*)d_in[1];
  float* out = (float*)d_out;

  dim3 grd(PP, NN, CSPLIT);
  dim3 blk(256);
  patches_kernel<<<grd, blk, 0, stream>>>(fm, grid, out);
}